// Round 1
// baseline (71.972 us; speedup 1.0000x reference)
//
#include <hip/hip_runtime.h>

#define NRULE 100
#define NB    32
#define NE    15000
#define NTOT  (NB * NE)   // 480000
#define HD    16
#define KMID  128
#define LN_EPS 1e-5f

// Precompute c[k] = b1[k] + sum_h rel[h] * W1[(H+h)*128 + k]  (rel = relation_emb[all_r[0]])
__global__ void precompute_c_kernel(const int* __restrict__ all_r,
                                    const float* __restrict__ relemb,
                                    const float* __restrict__ W1,
                                    const float* __restrict__ b1,
                                    float* __restrict__ cvec)
{
    const int k = threadIdx.x;
    if (k >= KMID) return;
    const int r = all_r[0];
    float t = b1[k];
#pragma unroll
    for (int h = 0; h < HD; ++h)
        t = fmaf(relemb[r * HD + h], W1[(HD + h) * KMID + k], t);
    cvec[k] = t;
}

__global__ __launch_bounds__(256) void predictor_main_kernel(
    const int*   __restrict__ rc,     // [R, B*E]
    const float* __restrict__ remb,   // [R, 16]
    const float* __restrict__ ln_g,
    const float* __restrict__ ln_b,
    const float* __restrict__ W1,     // [32, 128] row-major; we use rows 0..15
    const float* __restrict__ W2,     // [128]
    const float* __restrict__ b2,     // [1]
    const float* __restrict__ bias,   // [E]
    const float* __restrict__ cvec,   // [128] precomputed
    float* __restrict__ out)          // [B*E]
{
    const int tid  = blockIdx.x * blockDim.x + threadIdx.x;
    const int base = tid * 2;
    if (base >= NTOT) return;

    float acc0[HD], acc1[HD];
#pragma unroll
    for (int h = 0; h < HD; ++h) { acc0[h] = 0.f; acc1[h] = 0.f; }
    float ws0 = 0.f, ws1 = 0.f;

    const int* rcp = rc + base;
#pragma unroll 4
    for (int r = 0; r < NRULE; ++r) {
        const int2 p = *reinterpret_cast<const int2*>(rcp + r * NTOT);
        const float v0 = (float)p.x;
        const float v1 = (float)p.y;
        ws0 += v0; ws1 += v1;
#pragma unroll
        for (int h = 0; h < HD; ++h) {
            const float w = remb[r * HD + h];   // wave-uniform -> s_load / SGPR operand
            acc0[h] = fmaf(v0, w, acc0[h]);
            acc1[h] = fmaf(v1, w, acc1[h]);
        }
    }

    // LayerNorm (over H=16) + ReLU
    float vv0[HD], vv1[HD];
    {
        float mu0 = 0.f, mu1 = 0.f;
#pragma unroll
        for (int h = 0; h < HD; ++h) { mu0 += acc0[h]; mu1 += acc1[h]; }
        mu0 *= (1.f / HD); mu1 *= (1.f / HD);
        float var0 = 0.f, var1 = 0.f;
#pragma unroll
        for (int h = 0; h < HD; ++h) {
            const float d0 = acc0[h] - mu0;
            const float d1 = acc1[h] - mu1;
            var0 = fmaf(d0, d0, var0);
            var1 = fmaf(d1, d1, var1);
        }
        var0 *= (1.f / HD); var1 *= (1.f / HD);
        const float ri0 = rsqrtf(var0 + LN_EPS);
        const float ri1 = rsqrtf(var1 + LN_EPS);
#pragma unroll
        for (int h = 0; h < HD; ++h) {
            const float g = ln_g[h], bb = ln_b[h];
            vv0[h] = fmaxf(fmaf((acc0[h] - mu0) * ri0, g, bb), 0.f);
            vv1[h] = fmaxf(fmaf((acc1[h] - mu1) * ri1, g, bb), 0.f);
        }
    }

    // MLP: out = W2^T relu(W1[0:16]^T vv + c) + b2, shared weight loads for both elems
    const float b2v = b2[0];
    float o0 = b2v, o1 = b2v;
#pragma unroll 1
    for (int kc = 0; kc < KMID; kc += 16) {
        float t0[16], t1[16];
#pragma unroll
        for (int kk = 0; kk < 16; ++kk) {
            const float c = cvec[kc + kk];
            t0[kk] = c; t1[kk] = c;
        }
#pragma unroll
        for (int h = 0; h < HD; ++h) {
            const float a0 = vv0[h], a1 = vv1[h];
#pragma unroll
            for (int kk = 0; kk < 16; ++kk) {
                const float w = W1[h * KMID + kc + kk];  // uniform -> SGPR
                t0[kk] = fmaf(a0, w, t0[kk]);
                t1[kk] = fmaf(a1, w, t1[kk]);
            }
        }
#pragma unroll
        for (int kk = 0; kk < 16; ++kk) {
            const float w2 = W2[kc + kk];
            o0 = fmaf(fmaxf(t0[kk], 0.f), w2, o0);
            o1 = fmaf(fmaxf(t1[kk], 0.f), w2, o1);
        }
    }

    // candidate mask + entity bias
    o0 = (ws0 > 0.f) ? o0 : 0.f;
    o1 = (ws1 > 0.f) ? o1 : 0.f;
    const int m = base % NE;           // base even, NE even -> m+1 < NE
    float2 res;
    res.x = o0 + bias[m];
    res.y = o1 + bias[m + 1];
    *reinterpret_cast<float2*>(out + base) = res;
}

extern "C" void kernel_launch(void* const* d_in, const int* in_sizes, int n_in,
                              void* d_out, int out_size, void* d_ws, size_t ws_size,
                              hipStream_t stream)
{
    const int*   all_r  = (const int*)d_in[1];
    const int*   rc     = (const int*)d_in[2];
    const float* remb   = (const float*)d_in[3];
    const float* relemb = (const float*)d_in[4];
    const float* ln_g   = (const float*)d_in[5];
    const float* ln_b   = (const float*)d_in[6];
    const float* W1     = (const float*)d_in[7];
    const float* b1     = (const float*)d_in[8];
    const float* W2     = (const float*)d_in[9];
    const float* b2     = (const float*)d_in[10];
    const float* bias   = (const float*)d_in[11];
    float* out  = (float*)d_out;
    float* cvec = (float*)d_ws;

    hipLaunchKernelGGL(precompute_c_kernel, dim3(1), dim3(128), 0, stream,
                       all_r, relemb, W1, b1, cvec);

    const int threads = NTOT / 2;                    // 240000
    const int blocks  = (threads + 255) / 256;       // 938
    hipLaunchKernelGGL(predictor_main_kernel, dim3(blocks), dim3(256), 0, stream,
                       rc, remb, ln_g, ln_b, W1, W2, b2, bias, cvec, out);
}